// Round 12
// baseline (281.421 us; speedup 1.0000x reference)
//
#include <hip/hip_runtime.h>

#define N_NODES   50000
#define N_EDGES   800000
#define DIM       96
#define N_GRAPHS  128
#define OUT_DIM   10
#define NPAD      50048        // 782 * 64 rows (gemm grid coverage)
#define NBINS     391          // coarse bins of 128 nodes
#define P1_BLOCKS 128
#define EPB       (N_EDGES / P1_BLOCKS)   // 6250
#define SLICECAP  48           // per (bin,block) slice capacity: Poisson(16), P(>=48)~1e-10
#define CAP       64           // per-node bucket capacity (Poisson(16) tail ~1e-20)
#define LPAD      104          // LDS agg row stride: 208B = 13x16B (b128-aligned rows)

#define CAST_NB   ((N_NODES * 12 + 255) / 256)        // 2344
#define CONV_NB   ((3 * DIM * 2 * DIM + 255) / 256)   // 216

typedef __attribute__((ext_vector_type(8))) short          short8;
typedef __attribute__((ext_vector_type(8))) unsigned short u16x8;
typedef __attribute__((ext_vector_type(4))) float          f32x4;

__device__ __forceinline__ float b2f(unsigned short u) {
    union { unsigned int i; float f; } v; v.i = ((unsigned int)u) << 16; return v.f;
}
__device__ __forceinline__ unsigned short f2b(float f) {   // round-to-nearest-even
    union { float f; unsigned int i; } v; v.f = f;
    unsigned int u = v.i;
    return (unsigned short)((u + 0x7fffu + ((u >> 16) & 1u)) >> 16);
}

// ---------------------------------------------------------------------------
// Fused {pass1 edge binning | cast x -> bf16 | build Bt}: independent work,
// grid-partitioned.  pass1: zero-global-atomic (rounds 8/9: same-address
// returning atomics ~120ns) — private slices, LDS cursors, plain writes.
// ---------------------------------------------------------------------------
__global__ __launch_bounds__(256) void prep_pass1(
    const float* __restrict__ x,  const float* __restrict__ W1,
    const float* __restrict__ W2, const int* __restrict__ src,
    const int* __restrict__ dst,  unsigned short* __restrict__ harr,
    unsigned short* __restrict__ Bt, int* __restrict__ binned,
    int* __restrict__ cnt)
{
    __shared__ int cur[NBINS];
    const int b = blockIdx.x;
    const int t = threadIdx.x;

    if (b < P1_BLOCKS) {
        const int e0 = b * EPB;
        for (int i = t; i < NBINS; i += 256) cur[i] = 0;
        __syncthreads();
        for (int e = e0 + t; e < e0 + EPB; e += 256) {
            const int d   = dst[e];
            const int bin = d >> 7;
            const int pos = atomicAdd(&cur[bin], 1);
            if (pos < SLICECAP)
                binned[((size_t)bin * P1_BLOCKS + b) * SLICECAP + pos]
                    = ((d & 127) << 16) | src[e];
        }
        __syncthreads();
        for (int i = t; i < NBINS; i += 256)
            cnt[i * P1_BLOCKS + b] = min(cur[i], SLICECAP);
    } else if (b < P1_BLOCKS + CAST_NB) {
        const int tid = (b - P1_BLOCKS) * 256 + t;    // one per 8 cols
        if (tid >= N_NODES * 12) return;
        const int node = tid / 12;
        const int c    = (tid - node * 12) * 8;
        const float4 v0 = *(const float4*)(x + (size_t)node * DIM + c);
        const float4 v1 = *(const float4*)(x + (size_t)node * DIM + c + 4);
        u16x8 o;
        o[0] = f2b(v0.x); o[1] = f2b(v0.y); o[2] = f2b(v0.z); o[3] = f2b(v0.w);
        o[4] = f2b(v1.x); o[5] = f2b(v1.y); o[6] = f2b(v1.z); o[7] = f2b(v1.w);
        *(u16x8*)(harr + (size_t)node * DIM + c) = o;
    } else {
        const int idx = (b - P1_BLOCKS - CAST_NB) * 256 + t;  // Bt[l][n][k]
        if (idx >= 3 * DIM * 2 * DIM) return;
        const int l   = idx / (DIM * 2 * DIM);
        const int rem = idx - l * (DIM * 2 * DIM);
        const int n   = rem / (2 * DIM);
        const int k   = rem - n * (2 * DIM);
        const float v = (k < DIM) ? W1[(size_t)l * DIM * DIM + k * DIM + n]
                                  : W2[(size_t)l * DIM * DIM + (k - DIM) * DIM + n];
        Bt[idx] = f2b(v);
    }
}

// ---------------------------------------------------------------------------
// Pass 2: one block per bin (128 nodes).  Two threads per slice (parity
// split); LDS per-node cursors claim csrc slots.  No global atomics.
// ---------------------------------------------------------------------------
__global__ __launch_bounds__(256) void pass2_scatter(const int* __restrict__ cnt,
                                                     const int* __restrict__ binned,
                                                     int* __restrict__ csrc,
                                                     int* __restrict__ deg)
{
    __shared__ int ncnt[128];
    const int bin = blockIdx.x;
    const int t   = threadIdx.x;
    const int n0  = bin << 7;

    if (t < 128) ncnt[t] = 0;
    __syncthreads();

    const int slice = t >> 1;        // 0..127
    const int par   = t & 1;
    const int c     = cnt[bin * P1_BLOCKS + slice];
    const int* __restrict__ bb = binned + ((size_t)bin * P1_BLOCKS + slice) * SLICECAP;

    for (int i = par; i < c; i += 2) {
        const int v    = bb[i];
        const int dlow = v >> 16;
        const int s    = v & 0xffff;                  // src fits 16 bits (N<65536)
        const int pos  = atomicAdd(&ncnt[dlow], 1);   // LDS atomic
        if (pos < CAP) csrc[(size_t)(n0 + dlow) * CAP + pos] = s;
    }
    __syncthreads();

    if (t < 128 && n0 + t < N_NODES) deg[n0 + t] = min(ncnt[t], CAP);
}

// ---------------------------------------------------------------------------
// Fused layer.  Phase 1 gather: UNROLL 8 -> 16 row-half loads in flight per
// thread (latency-hiding theory: outstanding-bytes/CU doubles 147->293KB).
// __launch_bounds__(384,5) caps VGPR at 102 -> still 3 blocks/CU.
// Phase 2: mfma_f32_16x16x32_bf16, A-frag A[m=lane&15][k=quad*8+j], C/D
// col=lane&15,row=quad*4+reg (m89-verified); bfrag hoisted above the gather.
// Epilogue: acc -> LDS tile -> coalesced u16x8 stores.
// ---------------------------------------------------------------------------
__global__ __launch_bounds__(384, 5) void gnn_layer(
    const unsigned short* __restrict__ harr, const int* __restrict__ deg,
    const int* __restrict__ csrc, const unsigned short* __restrict__ Btl,
    unsigned short* __restrict__ hout)
{
    __shared__ unsigned short aggLds[64][LPAD];
    const int t       = threadIdx.x;
    const int rowBase = blockIdx.x * 64;

    // hoisted B fragments (overlap with gather)
    const int lane = t & 63;
    const int w    = t >> 6;    // 0..5 col tile
    const int m    = lane & 15;
    const int q    = lane >> 4;
    short8 bfrag[6];
#pragma unroll
    for (int s = 0; s < 6; s++)
        bfrag[s] = *(const short8*)(Btl + (size_t)(w * 16 + m) * (2 * DIM) + s * 32 + q * 8);

    // ---- phase 1: gather (unroll 8) ----
    {
        const int r    = t / 6;          // 0..63
        const int sub  = t - r * 6;      // 0..5
        const int node = rowBase + r;
        const int off  = sub * 16;       // 16 bf16 = 32B per thread

        float a[16];
#pragma unroll
        for (int i = 0; i < 16; i++) a[i] = 0.f;

        if (node < N_NODES) {
            const int d = deg[node];
            const int* __restrict__ bkt = csrc + (size_t)node * CAP;
            const unsigned short* __restrict__ hb = harr + off;

            int c = 0;
            for (; c + 8 <= d; c += 8) {
                const int4 s0 = *(const int4*)(bkt + c);
                const int4 s1 = *(const int4*)(bkt + c + 4);
                const unsigned short* p0 = hb + (size_t)s0.x * DIM;
                const unsigned short* p1 = hb + (size_t)s0.y * DIM;
                const unsigned short* p2 = hb + (size_t)s0.z * DIM;
                const unsigned short* p3 = hb + (size_t)s0.w * DIM;
                const unsigned short* p4 = hb + (size_t)s1.x * DIM;
                const unsigned short* p5 = hb + (size_t)s1.y * DIM;
                const unsigned short* p6 = hb + (size_t)s1.z * DIM;
                const unsigned short* p7 = hb + (size_t)s1.w * DIM;
                const u16x8 va0 = *(const u16x8*)(p0), vb0 = *(const u16x8*)(p0 + 8);
                const u16x8 va1 = *(const u16x8*)(p1), vb1 = *(const u16x8*)(p1 + 8);
                const u16x8 va2 = *(const u16x8*)(p2), vb2 = *(const u16x8*)(p2 + 8);
                const u16x8 va3 = *(const u16x8*)(p3), vb3 = *(const u16x8*)(p3 + 8);
                const u16x8 va4 = *(const u16x8*)(p4), vb4 = *(const u16x8*)(p4 + 8);
                const u16x8 va5 = *(const u16x8*)(p5), vb5 = *(const u16x8*)(p5 + 8);
                const u16x8 va6 = *(const u16x8*)(p6), vb6 = *(const u16x8*)(p6 + 8);
                const u16x8 va7 = *(const u16x8*)(p7), vb7 = *(const u16x8*)(p7 + 8);
#pragma unroll
                for (int i = 0; i < 8; i++) {
                    a[i]     += b2f(va0[i]) + b2f(va1[i]) + b2f(va2[i]) + b2f(va3[i])
                              + b2f(va4[i]) + b2f(va5[i]) + b2f(va6[i]) + b2f(va7[i]);
                    a[i + 8] += b2f(vb0[i]) + b2f(vb1[i]) + b2f(vb2[i]) + b2f(vb3[i])
                              + b2f(vb4[i]) + b2f(vb5[i]) + b2f(vb6[i]) + b2f(vb7[i]);
                }
            }
            if (c + 4 <= d) {
                const int4 s = *(const int4*)(bkt + c);
                const unsigned short* p0 = hb + (size_t)s.x * DIM;
                const unsigned short* p1 = hb + (size_t)s.y * DIM;
                const unsigned short* p2 = hb + (size_t)s.z * DIM;
                const unsigned short* p3 = hb + (size_t)s.w * DIM;
                const u16x8 va0 = *(const u16x8*)(p0), vb0 = *(const u16x8*)(p0 + 8);
                const u16x8 va1 = *(const u16x8*)(p1), vb1 = *(const u16x8*)(p1 + 8);
                const u16x8 va2 = *(const u16x8*)(p2), vb2 = *(const u16x8*)(p2 + 8);
                const u16x8 va3 = *(const u16x8*)(p3), vb3 = *(const u16x8*)(p3 + 8);
#pragma unroll
                for (int i = 0; i < 8; i++) {
                    a[i]     += b2f(va0[i]) + b2f(va1[i]) + b2f(va2[i]) + b2f(va3[i]);
                    a[i + 8] += b2f(vb0[i]) + b2f(vb1[i]) + b2f(vb2[i]) + b2f(vb3[i]);
                }
                c += 4;
            }
            for (; c < d; c++) {
                const unsigned short* p0 = hb + (size_t)bkt[c] * DIM;
                const u16x8 va0 = *(const u16x8*)(p0), vb0 = *(const u16x8*)(p0 + 8);
#pragma unroll
                for (int i = 0; i < 8; i++) {
                    a[i]     += b2f(va0[i]);
                    a[i + 8] += b2f(vb0[i]);
                }
            }
        }

        u16x8 o0, o1;
#pragma unroll
        for (int i = 0; i < 8; i++) { o0[i] = f2b(a[i]); o1[i] = f2b(a[i + 8]); }
        *(u16x8*)(&aggLds[r][off])     = o0;
        *(u16x8*)(&aggLds[r][off + 8]) = o1;
    }
    __syncthreads();

    // ---- phase 2: MFMA (all accs first; aggLds still holds the agg tile) ----
    f32x4 accv[4];
#pragma unroll
    for (int r = 0; r < 4; r++) {
        const int rb = rowBase + r * 16;
        f32x4 acc = {0.f, 0.f, 0.f, 0.f};
        const unsigned short* ah = harr + (size_t)(rb + m) * DIM + q * 8;
#pragma unroll
        for (int s = 0; s < 3; s++) {
            const short8 af = *(const short8*)(ah + s * 32);
            acc = __builtin_amdgcn_mfma_f32_16x16x32_bf16(af, bfrag[s], acc, 0, 0, 0);
        }
#pragma unroll
        for (int s = 0; s < 3; s++) {
            const short8 af = *(const short8*)(&aggLds[r * 16 + m][s * 32 + q * 8]);
            acc = __builtin_amdgcn_mfma_f32_16x16x32_bf16(af, bfrag[s + 3], acc, 0, 0, 0);
        }
        accv[r] = acc;
    }
    __syncthreads();            // all aggLds reads done; safe to overwrite

    // ---- epilogue: acc -> LDS -> coalesced stores ----
#pragma unroll
    for (int r = 0; r < 4; r++)
#pragma unroll
        for (int i = 0; i < 4; i++)
            aggLds[r * 16 + q * 4 + i][w * 16 + m] = f2b(fmaxf(accv[r][i], 0.f));
    __syncthreads();

#pragma unroll
    for (int k = 0; k < 2; k++) {
        const int idx = t + k * 384;     // 768 chunks: 64 rows x 12 x 16B
        const int row = idx / 12;
        const int ch  = idx - row * 12;
        const int grow = rowBase + row;
        if (grow < N_NODES)
            *(u16x8*)(hout + (size_t)grow * DIM + ch * 8)
                = *(const u16x8*)(&aggLds[row][ch * 8]);
    }
}

// ---------------------------------------------------------------------------
// Fused pool + classifier, 960 threads (10-way row split for the pooling walk).
// ---------------------------------------------------------------------------
__global__ __launch_bounds__(960) void pool_classify(
    const unsigned short* __restrict__ h, const int* __restrict__ batch,
    const float* __restrict__ cw1, const float* __restrict__ cb1,
    const float* __restrict__ cw2, const float* __restrict__ cb2,
    float* __restrict__ out)
{
    const int g = blockIdx.x;
    const int t = threadIdx.x;

    int lo = 0, hi = N_NODES;
    while (lo < hi) { int m = (lo + hi) >> 1; if (batch[m] < g) lo = m + 1; else hi = m; }
    const int start = lo;
    hi = N_NODES;
    while (lo < hi) { int m = (lo + hi) >> 1; if (batch[m] < g + 1) lo = m + 1; else hi = m; }
    const int end = lo;

    __shared__ float part[10][DIM];
    __shared__ float gr[DIM];
    __shared__ float hid[DIM];

    const int col = t % DIM;     // 0..95
    const int ty  = t / DIM;     // 0..9

    float s = 0.f;
    for (int n = start + ty; n < end; n += 10)
        s += b2f(h[(size_t)n * DIM + col]);
    part[ty][col] = s;
    __syncthreads();
    if (ty == 0) {
        float acc = 0.f;
#pragma unroll
        for (int p = 0; p < 10; p++) acc += part[p][col];
        gr[col] = acc;
    }
    __syncthreads();

    if (ty < 4) {                // hidden = relu(gr @ cw1 + cb1), k split 4-way
        float hsum = 0.f;
        const int k0 = ty * (DIM / 4);
#pragma unroll 4
        for (int k = k0; k < k0 + DIM / 4; k++)
            hsum += gr[k] * cw1[k * DIM + col];
        part[ty][col] = hsum;
    }
    __syncthreads();
    if (ty == 0)
        hid[col] = fmaxf(part[0][col] + part[1][col] + part[2][col] + part[3][col]
                         + cb1[col], 0.f);
    __syncthreads();

    if (t < OUT_DIM) {
        float o = cb2[t];
#pragma unroll 4
        for (int k = 0; k < DIM; k++) o += hid[k] * cw2[k * OUT_DIM + t];
        out[g * OUT_DIM + t] = o;
    }
}

// ---------------------------------------------------------------------------
extern "C" void kernel_launch(void* const* d_in, const int* in_sizes, int n_in,
                              void* d_out, int out_size, void* d_ws, size_t ws_size,
                              hipStream_t stream)
{
    const float* x     = (const float*)d_in[0];
    const int*   ei    = (const int*)  d_in[1];
    const int*   batch = (const int*)  d_in[2];
    const float* W1    = (const float*)d_in[3];
    const float* W2    = (const float*)d_in[4];
    const float* cw1   = (const float*)d_in[5];
    const float* cb1   = (const float*)d_in[6];
    const float* cw2   = (const float*)d_in[7];
    const float* cb2   = (const float*)d_in[8];
    float*       out   = (float*)d_out;

    const int* src = ei;             // edge_index[0]
    const int* dst = ei + N_EDGES;   // edge_index[1]

    // workspace layout (16B-aligned at each boundary)
    unsigned short* bufA = (unsigned short*)d_ws;          // [NPAD,96] bf16
    unsigned short* bufB = bufA + (size_t)NPAD * DIM;      // [NPAD,96] bf16
    unsigned short* Bt   = bufB + (size_t)NPAD * DIM;      // [3,96,192] bf16
    int*   cnt    = (int*)(Bt + 3 * DIM * 2 * DIM);        // [NBINS*P1_BLOCKS]
    int*   binned = cnt + NBINS * P1_BLOCKS;               // [NBINS*P1_BLOCKS*SLICECAP]
    int*   csrc   = binned + (size_t)NBINS * P1_BLOCKS * SLICECAP; // [N*CAP]
    int*   deg    = csrc + (size_t)N_NODES * CAP;          // [N]

    prep_pass1<<<P1_BLOCKS + CAST_NB + CONV_NB, 256, 0, stream>>>(
        x, W1, W2, src, dst, bufA, Bt, binned, cnt);
    pass2_scatter<<<NBINS, 256, 0, stream>>>(cnt, binned, csrc, deg);

    unsigned short* hin  = bufA;
    unsigned short* hout = bufB;
    for (int l = 0; l < 3; l++) {
        gnn_layer<<<NPAD / 64, 384, 0, stream>>>(hin, deg, csrc,
                                                 Bt + (size_t)l * DIM * 2 * DIM, hout);
        unsigned short* tmp = hin; hin = hout; hout = tmp;
    }

    pool_classify<<<N_GRAPHS, 960, 0, stream>>>(hin, batch, cw1, cb1, cw2, cb2, out);
}

// Round 13
// 256.157 us; speedup vs baseline: 1.0986x; 1.0986x over previous
//
#include <hip/hip_runtime.h>

#define N_NODES   50000
#define N_EDGES   800000
#define DIM       96
#define N_GRAPHS  128
#define OUT_DIM   10
#define NPAD      50048        // 1564 * 32 rows (gemm grid coverage)
#define NBINS     391          // coarse bins of 128 nodes
#define P1_BLOCKS 128
#define EPB       (N_EDGES / P1_BLOCKS)   // 6250
#define SLICECAP  48           // per (bin,block) slice capacity: Poisson(16), P(>=48)~1e-10
#define CAP       64           // per-node bucket capacity (Poisson(16) tail ~1e-20)
#define LPAD      104          // LDS agg row stride: 208B = 13x16B (b128-aligned rows)

#define CAST_NB   ((N_NODES * 12 + 255) / 256)        // 2344
#define CONV_NB   ((3 * DIM * 2 * DIM + 255) / 256)   // 216

typedef __attribute__((ext_vector_type(8))) short          short8;
typedef __attribute__((ext_vector_type(8))) unsigned short u16x8;
typedef __attribute__((ext_vector_type(4))) float          f32x4;

__device__ __forceinline__ float b2f(unsigned short u) {
    union { unsigned int i; float f; } v; v.i = ((unsigned int)u) << 16; return v.f;
}
__device__ __forceinline__ unsigned short f2b(float f) {   // round-to-nearest-even
    union { float f; unsigned int i; } v; v.f = f;
    unsigned int u = v.i;
    return (unsigned short)((u + 0x7fffu + ((u >> 16) & 1u)) >> 16);
}

// ---------------------------------------------------------------------------
// Fused {pass1 edge binning | cast x -> bf16 | build Bt}: independent work,
// grid-partitioned.  pass1: zero-global-atomic (rounds 8/9: same-address
// returning atomics ~120ns) — private slices, LDS cursors, plain writes.
// ---------------------------------------------------------------------------
__global__ __launch_bounds__(256) void prep_pass1(
    const float* __restrict__ x,  const float* __restrict__ W1,
    const float* __restrict__ W2, const int* __restrict__ src,
    const int* __restrict__ dst,  unsigned short* __restrict__ harr,
    unsigned short* __restrict__ Bt, int* __restrict__ binned,
    int* __restrict__ cnt)
{
    __shared__ int cur[NBINS];
    const int b = blockIdx.x;
    const int t = threadIdx.x;

    if (b < P1_BLOCKS) {
        const int e0 = b * EPB;
        for (int i = t; i < NBINS; i += 256) cur[i] = 0;
        __syncthreads();
        for (int e = e0 + t; e < e0 + EPB; e += 256) {
            const int d   = dst[e];
            const int bin = d >> 7;
            const int pos = atomicAdd(&cur[bin], 1);
            if (pos < SLICECAP)
                binned[((size_t)bin * P1_BLOCKS + b) * SLICECAP + pos]
                    = ((d & 127) << 16) | src[e];
        }
        __syncthreads();
        for (int i = t; i < NBINS; i += 256)
            cnt[i * P1_BLOCKS + b] = min(cur[i], SLICECAP);
    } else if (b < P1_BLOCKS + CAST_NB) {
        const int tid = (b - P1_BLOCKS) * 256 + t;    // one per 8 cols
        if (tid >= N_NODES * 12) return;
        const int node = tid / 12;
        const int c    = (tid - node * 12) * 8;
        const float4 v0 = *(const float4*)(x + (size_t)node * DIM + c);
        const float4 v1 = *(const float4*)(x + (size_t)node * DIM + c + 4);
        u16x8 o;
        o[0] = f2b(v0.x); o[1] = f2b(v0.y); o[2] = f2b(v0.z); o[3] = f2b(v0.w);
        o[4] = f2b(v1.x); o[5] = f2b(v1.y); o[6] = f2b(v1.z); o[7] = f2b(v1.w);
        *(u16x8*)(harr + (size_t)node * DIM + c) = o;
    } else {
        const int idx = (b - P1_BLOCKS - CAST_NB) * 256 + t;  // Bt[l][n][k]
        if (idx >= 3 * DIM * 2 * DIM) return;
        const int l   = idx / (DIM * 2 * DIM);
        const int rem = idx - l * (DIM * 2 * DIM);
        const int n   = rem / (2 * DIM);
        const int k   = rem - n * (2 * DIM);
        const float v = (k < DIM) ? W1[(size_t)l * DIM * DIM + k * DIM + n]
                                  : W2[(size_t)l * DIM * DIM + (k - DIM) * DIM + n];
        Bt[idx] = f2b(v);
    }
}

// ---------------------------------------------------------------------------
// Pass 2: one block per bin (128 nodes).  Two threads per slice (parity
// split); LDS per-node cursors claim csrc slots.  No global atomics.
// ---------------------------------------------------------------------------
__global__ __launch_bounds__(256) void pass2_scatter(const int* __restrict__ cnt,
                                                     const int* __restrict__ binned,
                                                     int* __restrict__ csrc,
                                                     int* __restrict__ deg)
{
    __shared__ int ncnt[128];
    const int bin = blockIdx.x;
    const int t   = threadIdx.x;
    const int n0  = bin << 7;

    if (t < 128) ncnt[t] = 0;
    __syncthreads();

    const int slice = t >> 1;        // 0..127
    const int par   = t & 1;
    const int c     = cnt[bin * P1_BLOCKS + slice];
    const int* __restrict__ bb = binned + ((size_t)bin * P1_BLOCKS + slice) * SLICECAP;

    for (int i = par; i < c; i += 2) {
        const int v    = bb[i];
        const int dlow = v >> 16;
        const int s    = v & 0xffff;                  // src fits 16 bits (N<65536)
        const int pos  = atomicAdd(&ncnt[dlow], 1);   // LDS atomic
        if (pos < CAP) csrc[(size_t)(n0 + dlow) * CAP + pos] = s;
    }
    __syncthreads();

    if (t < 128 && n0 + t < N_NODES) deg[n0 + t] = min(ncnt[t], CAP);
}

// ---------------------------------------------------------------------------
// Fused layer, 32-ROW BLOCKS (round-12 lesson: VGPR=64 is the occupancy cliff;
// fatter threads spill — more waves is the only way to raise outstanding
// loads/CU).  12 threads x 16B per row; unroll 8 -> 8 loads in flight at ~56
// VGPR; grid 1564 -> ~30 resident waves/CU (was ~18).
// Phase 2: mfma_f32_16x16x32_bf16, A-frag A[m=lane&15][k=quad*8+j], C/D
// col=lane&15,row=quad*4+reg (m89-verified); bfrag hoisted above the gather.
// Epilogue: acc -> LDS tile -> coalesced u16x8 stores (1 chunk/thread).
// ---------------------------------------------------------------------------
__global__ __launch_bounds__(384) void gnn_layer(
    const unsigned short* __restrict__ harr, const int* __restrict__ deg,
    const int* __restrict__ csrc, const unsigned short* __restrict__ Btl,
    unsigned short* __restrict__ hout)
{
    __shared__ unsigned short aggLds[32][LPAD];
    const int t       = threadIdx.x;
    const int rowBase = blockIdx.x * 32;

    // hoisted B fragments (overlap with gather)
    const int lane = t & 63;
    const int w    = t >> 6;    // 0..5 col tile
    const int m    = lane & 15;
    const int q    = lane >> 4;
    short8 bfrag[6];
#pragma unroll
    for (int s = 0; s < 6; s++)
        bfrag[s] = *(const short8*)(Btl + (size_t)(w * 16 + m) * (2 * DIM) + s * 32 + q * 8);

    // ---- phase 1: gather (12 thr/row x 16B, unroll 8) ----
    {
        const int r    = t / 12;         // 0..31
        const int sub  = t - r * 12;     // 0..11
        const int node = rowBase + r;
        const int off  = sub * 8;        // 8 bf16 = 16B per thread

        float a[8];
#pragma unroll
        for (int i = 0; i < 8; i++) a[i] = 0.f;

        if (node < N_NODES) {
            const int d = deg[node];
            const int* __restrict__ bkt = csrc + (size_t)node * CAP;
            const unsigned short* __restrict__ hb = harr + off;

            int c = 0;
            for (; c + 8 <= d; c += 8) {
                const int4 s0 = *(const int4*)(bkt + c);
                const int4 s1 = *(const int4*)(bkt + c + 4);
                const u16x8 v0 = *(const u16x8*)(hb + (size_t)s0.x * DIM);
                const u16x8 v1 = *(const u16x8*)(hb + (size_t)s0.y * DIM);
                const u16x8 v2 = *(const u16x8*)(hb + (size_t)s0.z * DIM);
                const u16x8 v3 = *(const u16x8*)(hb + (size_t)s0.w * DIM);
                const u16x8 v4 = *(const u16x8*)(hb + (size_t)s1.x * DIM);
                const u16x8 v5 = *(const u16x8*)(hb + (size_t)s1.y * DIM);
                const u16x8 v6 = *(const u16x8*)(hb + (size_t)s1.z * DIM);
                const u16x8 v7 = *(const u16x8*)(hb + (size_t)s1.w * DIM);
#pragma unroll
                for (int i = 0; i < 8; i++)
                    a[i] += b2f(v0[i]) + b2f(v1[i]) + b2f(v2[i]) + b2f(v3[i])
                          + b2f(v4[i]) + b2f(v5[i]) + b2f(v6[i]) + b2f(v7[i]);
            }
            if (c + 4 <= d) {
                const int4 s = *(const int4*)(bkt + c);
                const u16x8 v0 = *(const u16x8*)(hb + (size_t)s.x * DIM);
                const u16x8 v1 = *(const u16x8*)(hb + (size_t)s.y * DIM);
                const u16x8 v2 = *(const u16x8*)(hb + (size_t)s.z * DIM);
                const u16x8 v3 = *(const u16x8*)(hb + (size_t)s.w * DIM);
#pragma unroll
                for (int i = 0; i < 8; i++)
                    a[i] += b2f(v0[i]) + b2f(v1[i]) + b2f(v2[i]) + b2f(v3[i]);
                c += 4;
            }
            for (; c < d; c++) {
                const u16x8 v0 = *(const u16x8*)(hb + (size_t)bkt[c] * DIM);
#pragma unroll
                for (int i = 0; i < 8; i++) a[i] += b2f(v0[i]);
            }
        }

        u16x8 o;
#pragma unroll
        for (int i = 0; i < 8; i++) o[i] = f2b(a[i]);
        *(u16x8*)(&aggLds[r][off]) = o;
    }
    __syncthreads();

    // ---- phase 2: MFMA (2 row-tiles; aggLds still holds the agg tile) ----
    f32x4 accv[2];
#pragma unroll
    for (int r = 0; r < 2; r++) {
        const int rb = rowBase + r * 16;
        f32x4 acc = {0.f, 0.f, 0.f, 0.f};
        const unsigned short* ah = harr + (size_t)(rb + m) * DIM + q * 8;
#pragma unroll
        for (int s = 0; s < 3; s++) {
            const short8 af = *(const short8*)(ah + s * 32);
            acc = __builtin_amdgcn_mfma_f32_16x16x32_bf16(af, bfrag[s], acc, 0, 0, 0);
        }
#pragma unroll
        for (int s = 0; s < 3; s++) {
            const short8 af = *(const short8*)(&aggLds[r * 16 + m][s * 32 + q * 8]);
            acc = __builtin_amdgcn_mfma_f32_16x16x32_bf16(af, bfrag[s + 3], acc, 0, 0, 0);
        }
        accv[r] = acc;
    }
    __syncthreads();            // all aggLds reads done; safe to overwrite

    // ---- epilogue: acc -> LDS -> coalesced stores ----
#pragma unroll
    for (int r = 0; r < 2; r++)
#pragma unroll
        for (int i = 0; i < 4; i++)
            aggLds[r * 16 + q * 4 + i][w * 16 + m] = f2b(fmaxf(accv[r][i], 0.f));
    __syncthreads();

    {
        const int row = t / 12;          // 384 chunks: 32 rows x 12 x 16B
        const int ch  = t - row * 12;
        const int grow = rowBase + row;
        if (grow < N_NODES)
            *(u16x8*)(hout + (size_t)grow * DIM + ch * 8)
                = *(const u16x8*)(&aggLds[row][ch * 8]);
    }
}

// ---------------------------------------------------------------------------
// Fused pool + classifier, 960 threads (10-way row split for the pooling walk).
// ---------------------------------------------------------------------------
__global__ __launch_bounds__(960) void pool_classify(
    const unsigned short* __restrict__ h, const int* __restrict__ batch,
    const float* __restrict__ cw1, const float* __restrict__ cb1,
    const float* __restrict__ cw2, const float* __restrict__ cb2,
    float* __restrict__ out)
{
    const int g = blockIdx.x;
    const int t = threadIdx.x;

    int lo = 0, hi = N_NODES;
    while (lo < hi) { int m = (lo + hi) >> 1; if (batch[m] < g) lo = m + 1; else hi = m; }
    const int start = lo;
    hi = N_NODES;
    while (lo < hi) { int m = (lo + hi) >> 1; if (batch[m] < g + 1) lo = m + 1; else hi = m; }
    const int end = lo;

    __shared__ float part[10][DIM];
    __shared__ float gr[DIM];
    __shared__ float hid[DIM];

    const int col = t % DIM;     // 0..95
    const int ty  = t / DIM;     // 0..9

    float s = 0.f;
    for (int n = start + ty; n < end; n += 10)
        s += b2f(h[(size_t)n * DIM + col]);
    part[ty][col] = s;
    __syncthreads();
    if (ty == 0) {
        float acc = 0.f;
#pragma unroll
        for (int p = 0; p < 10; p++) acc += part[p][col];
        gr[col] = acc;
    }
    __syncthreads();

    if (ty < 4) {                // hidden = relu(gr @ cw1 + cb1), k split 4-way
        float hsum = 0.f;
        const int k0 = ty * (DIM / 4);
#pragma unroll 4
        for (int k = k0; k < k0 + DIM / 4; k++)
            hsum += gr[k] * cw1[k * DIM + col];
        part[ty][col] = hsum;
    }
    __syncthreads();
    if (ty == 0)
        hid[col] = fmaxf(part[0][col] + part[1][col] + part[2][col] + part[3][col]
                         + cb1[col], 0.f);
    __syncthreads();

    if (t < OUT_DIM) {
        float o = cb2[t];
#pragma unroll 4
        for (int k = 0; k < DIM; k++) o += hid[k] * cw2[k * OUT_DIM + t];
        out[g * OUT_DIM + t] = o;
    }
}

// ---------------------------------------------------------------------------
extern "C" void kernel_launch(void* const* d_in, const int* in_sizes, int n_in,
                              void* d_out, int out_size, void* d_ws, size_t ws_size,
                              hipStream_t stream)
{
    const float* x     = (const float*)d_in[0];
    const int*   ei    = (const int*)  d_in[1];
    const int*   batch = (const int*)  d_in[2];
    const float* W1    = (const float*)d_in[3];
    const float* W2    = (const float*)d_in[4];
    const float* cw1   = (const float*)d_in[5];
    const float* cb1   = (const float*)d_in[6];
    const float* cw2   = (const float*)d_in[7];
    const float* cb2   = (const float*)d_in[8];
    float*       out   = (float*)d_out;

    const int* src = ei;             // edge_index[0]
    const int* dst = ei + N_EDGES;   // edge_index[1]

    // workspace layout (16B-aligned at each boundary)
    unsigned short* bufA = (unsigned short*)d_ws;          // [NPAD,96] bf16
    unsigned short* bufB = bufA + (size_t)NPAD * DIM;      // [NPAD,96] bf16
    unsigned short* Bt   = bufB + (size_t)NPAD * DIM;      // [3,96,192] bf16
    int*   cnt    = (int*)(Bt + 3 * DIM * 2 * DIM);        // [NBINS*P1_BLOCKS]
    int*   binned = cnt + NBINS * P1_BLOCKS;               // [NBINS*P1_BLOCKS*SLICECAP]
    int*   csrc   = binned + (size_t)NBINS * P1_BLOCKS * SLICECAP; // [N*CAP]
    int*   deg    = csrc + (size_t)N_NODES * CAP;          // [N]

    prep_pass1<<<P1_BLOCKS + CAST_NB + CONV_NB, 256, 0, stream>>>(
        x, W1, W2, src, dst, bufA, Bt, binned, cnt);
    pass2_scatter<<<NBINS, 256, 0, stream>>>(cnt, binned, csrc, deg);

    unsigned short* hin  = bufA;
    unsigned short* hout = bufB;
    for (int l = 0; l < 3; l++) {
        gnn_layer<<<NPAD / 32, 384, 0, stream>>>(hin, deg, csrc,
                                                 Bt + (size_t)l * DIM * 2 * DIM, hout);
        unsigned short* tmp = hin; hin = hout; hout = tmp;
    }

    pool_classify<<<N_GRAPHS, 960, 0, stream>>>(hin, batch, cw1, cb1, cw2, cb2, out);
}